// Round 5
// baseline (30.679 us; speedup 1.0000x reference)
//
#include <hip/hip_runtime.h>
#include <hip/hip_bf16.h>

// DecoderBlock: block-sparse masked linear (8 GEMMs M=256,N=1024,K=1024)
// + BatchNorm1d (batch stats; bias cancels exactly) + Swish.
// FUSED single-output kernel: block = full batch (256 rows) x 32 features ->
// BN stats block-local. grid 256 = 8 g x 32 nt; g=bid&7 -> XCD-local x slice.
// Structure: 4 mega-steps of BK=256. W: reg-staged (load-early/write-late,
// T14) into double-buffered 16KB B-LDS (XOR-swizzled). A(x, bf16): per-lane
// direct loads from L2 (rows are wave-exclusive -> LDS would buy nothing).
// 8 waves x (32x32) tile; 4 raw barriers total; no vmcnt drains mid-kernel.

typedef float  f32x4  __attribute__((ext_vector_type(4)));
typedef short  short8 __attribute__((ext_vector_type(8)));
typedef unsigned short u16x8 __attribute__((ext_vector_type(8)));
typedef unsigned int   u32x2 __attribute__((ext_vector_type(2)));

static __device__ __forceinline__ unsigned int f2bf(float f) {
    unsigned int u = __float_as_uint(f);
    u += 0x7FFFu + ((u >> 16) & 1u);          // RNE (inputs finite)
    return u >> 16;
}

// ---------------- x f32 -> bf16 (12 MB traffic; result L2/L3-resident) ----------------
__global__ __launch_bounds__(256) void conv_kernel(const float* __restrict__ x,
                                                   unsigned short* __restrict__ xb) {
    const int base = blockIdx.x * 1024 + threadIdx.x;
#pragma unroll
    for (int i = 0; i < 4; ++i) {
        const int cid = base + i * 256;               // 8-float chunk id
        const f32x4 a = *(const f32x4*)(x + (size_t)cid * 8);
        const f32x4 b = *(const f32x4*)(x + (size_t)cid * 8 + 4);
        u16x8 v;
        v[0] = f2bf(a[0]); v[1] = f2bf(a[1]); v[2] = f2bf(a[2]); v[3] = f2bf(a[3]);
        v[4] = f2bf(b[0]); v[5] = f2bf(b[1]); v[6] = f2bf(b[2]); v[7] = f2bf(b[3]);
        *(u16x8*)(xb + (size_t)cid * 8) = v;
    }
}

// ---------------- fused GEMM + BN + Swish ----------------
__global__ __launch_bounds__(512) void fused_kernel(
    const unsigned short* __restrict__ xb, const float* __restrict__ W,
    const float* __restrict__ gamma, const float* __restrict__ beta,
    float* __restrict__ out)
{
    __shared__ __align__(16) char Blds[2][16384];   // [32 n][256 k] bf16, swizzled
    __shared__ float wps1[8][32], wps2[8][32];
    __shared__ float sa[32], sb[32];

    const int bid = blockIdx.x;
    const int g   = bid & 7;               // channel group -> XCD (round-robin)
    const int nt  = bid >> 3;              // 0..31
    const int o   = g * 4 + (nt >> 3);
    const int f0  = (nt & 7) * 32;
    const int gcol0 = o * 256 + f0;

    const int t    = threadIdx.x;
    const int w    = t >> 6;               // wave 0..7 (rows w*32..w*32+31)
    const int lane = t & 63;
    const int lr   = lane & 15;
    const int kq   = lane >> 4;

    f32x4 acc[2][2];
    const f32x4 zero = {0.f, 0.f, 0.f, 0.f};
#pragma unroll
    for (int i = 0; i < 2; ++i) { acc[i][0] = zero; acc[i][1] = zero; }

    f32x4  wreg[4];                         // W stage regs (1 KB row per wave per q)
    short8 af[16];                          // A frags: [ks*2+i]

    const unsigned short* abase = xb + g * 1024 + (size_t)(w * 32 + lr) * 8192;

    auto WISSUE = [&](int st) {             // issue W loads: wave w reads rows q*8+w fully sequentially
        const float* Wb = W + ((size_t)((o * 32 + g * 4 + st) * 256 + f0)) * 256;
#pragma unroll
        for (int q = 0; q < 4; ++q)
            wreg[q] = *(const f32x4*)(Wb + (size_t)(q * 8 + w) * 256 + lane * 4);
    };
    auto WWRITE = [&](int buf) {            // cvt + swizzled ds_write_b64 (waits wreg via compiler)
#pragma unroll
        for (int q = 0; q < 4; ++q) {
            const int n = q * 8 + w;
            u32x2 d;
            d[0] = f2bf(wreg[q][0]) | (f2bf(wreg[q][1]) << 16);
            d[1] = f2bf(wreg[q][2]) | (f2bf(wreg[q][3]) << 16);
            *(u32x2*)(Blds[buf] + n * 512 + (((lane >> 1) ^ (n & 7)) * 16) + (lane & 1) * 8) = d;
        }
    };
    auto AISSUE = [&](int st) {             // 16 direct 16B loads, issue order = consumption order
#pragma unroll
        for (int ks = 0; ks < 8; ++ks)
#pragma unroll
            for (int i = 0; i < 2; ++i)
                af[ks * 2 + i] = *(const short8*)(abase + (size_t)i * 16 * 8192
                                                  + st * 256 + ks * 32 + kq * 8);
    };
    auto COMPUTE = [&](int buf) {
#pragma unroll
        for (int ks = 0; ks < 8; ++ks) {
            short8 bfr[2];
#pragma unroll
            for (int j = 0; j < 2; ++j) {
                const int n = j * 16 + lr;
                bfr[j] = *(const short8*)(Blds[buf] + n * 512 + (((ks * 4 + kq) ^ (n & 7)) * 16));
            }
#pragma unroll
            for (int i = 0; i < 2; ++i)
#pragma unroll
                for (int j = 0; j < 2; ++j)
                    acc[i][j] = __builtin_amdgcn_mfma_f32_16x16x32_bf16(af[ks * 2 + i], bfr[j], acc[i][j], 0, 0, 0);
        }
    };

    // prologue: stage B0; A(0)+W(1) prefetches stay in flight across the barrier
    WISSUE(0);
    WWRITE(0);
    AISSUE(0);
    WISSUE(1);
    asm volatile("s_waitcnt lgkmcnt(0)" ::: "memory");
    __builtin_amdgcn_s_barrier();

#pragma unroll
    for (int st = 0; st < 4; ++st) {
        COMPUTE(st & 1);
        if (st < 3) {
            WWRITE((st + 1) & 1);           // other buffer; all waves left it at last barrier
            AISSUE(st + 1);                 // reg-dest loads: safe to cross barrier
            if (st < 2) WISSUE(st + 2);
            asm volatile("s_waitcnt lgkmcnt(0)" ::: "memory");
            __builtin_amdgcn_s_barrier();
        }
    }

    // ---------------- fused BN + Swish epilogue ----------------
    float s1[2] = {0.f, 0.f}, s2[2] = {0.f, 0.f};
#pragma unroll
    for (int i = 0; i < 2; ++i)
#pragma unroll
        for (int j = 0; j < 2; ++j)
#pragma unroll
            for (int r = 0; r < 4; ++r) {
                const float v = acc[i][j][r];
                s1[j] += v; s2[j] += v * v;
            }
#pragma unroll
    for (int j = 0; j < 2; ++j) {           // reduce over kq groups -> per (lr,j) col sums
        s1[j] += __shfl_xor(s1[j], 16); s2[j] += __shfl_xor(s2[j], 16);
        s1[j] += __shfl_xor(s1[j], 32); s2[j] += __shfl_xor(s2[j], 32);
    }
    if (kq == 0) {
#pragma unroll
        for (int j = 0; j < 2; ++j) {
            wps1[w][j * 16 + lr] = s1[j];
            wps2[w][j * 16 + lr] = s2[j];
        }
    }
    __syncthreads();
    if (t < 32) {
        float a1 = 0.f, a2 = 0.f;
#pragma unroll
        for (int q = 0; q < 8; ++q) { a1 += wps1[q][t]; a2 += wps2[q][t]; }
        const float mean = a1 * (1.0f / 256.0f);
        const float var  = a2 * (1.0f / 256.0f) - mean * mean;   // biased (jnp.var)
        const float istd = rsqrtf(var + 1e-5f);
        const float ga = gamma[gcol0 + t];
        sa[t] = ga * istd;
        sb[t] = beta[gcol0 + t] - mean * ga * istd;
    }
    __syncthreads();

    // apply affine + swish; C/D layout col=lane&15, row=(lane>>4)*4+reg
#pragma unroll
    for (int i = 0; i < 2; ++i) {
        const int row0 = w * 32 + i * 16 + kq * 4;
#pragma unroll
        for (int j = 0; j < 2; ++j) {
            const int col = j * 16 + lr;
            const float a = sa[col], b2 = sb[col];
#pragma unroll
            for (int r = 0; r < 4; ++r) {
                const float z = a * acc[i][j][r] + b2;
                out[(size_t)(row0 + r) * 8192 + gcol0 + col] = z / (1.0f + expf(-z));
            }
        }
    }
}

extern "C" void kernel_launch(void* const* d_in, const int* in_sizes, int n_in,
                              void* d_out, int out_size, void* d_ws, size_t ws_size,
                              hipStream_t stream) {
    const float* x     = (const float*)d_in[0];
    const float* W     = (const float*)d_in[1];
    // d_in[2] = bias: cancelled exactly by BN mean subtraction -> unused
    const float* gamma = (const float*)d_in[3];
    const float* beta  = (const float*)d_in[4];
    // d_in[5] = mask: implicit in block structure -> unused
    float* out = (float*)d_out;

    unsigned short* xb = (unsigned short*)d_ws;   // 4MB bf16 x

    conv_kernel<<<256, 256, 0, stream>>>(x, xb);
    fused_kernel<<<256, 512, 0, stream>>>(xb, W, gamma, beta, out);
}